// Round 14
// baseline (193.370 us; speedup 1.0000x reference)
//
#include <hip/hip_runtime.h>
#include <math.h>

// ComplexEMA fused persistent kernel (R13 = R12 structure + SECOND-ORDER
// REAL recurrence, -40% core FLOPs).
// y[b,d,t] = Re(sum_n gam_dn * h_dn[t]) + omega_d * x[b,d,t]
// h = p*u;  u' = q*u + x (complex).  Since x is REAL and q = a+ib satisfies
// z^2 - 2a z + c = 0 (c=|q|^2), track ONE real state per mode:
//     s[t] = 2a*s[t-1] - c*s[t-2] + x[t]        (2 FMA; s[t-2] is a rename)
// with  ur = s - a*s_prev,  ui = b*s_prev  (verified: t=0,1 by hand).
// y-accum: Re(g*u) = c1*s_new + c2*s_old, c1=gr, c2=gi*b-gr*a.
// Scan in (s,sp) space: M^k = alpha*M - c*beta*I (companion matrix satisfies
// its own char poly) -> 2 scalars/mode; doubling alpha'=2alpha(a*alpha-c*beta),
// beta'=alpha^2-c*beta^2; product (W*=M^s): a''=2a*t1-c*t3, b''=t1-c*t2 with
// t1=Wa*al, t2=Wb*be, t3=Wa*be+al*Wb.
//
// Rationale: R11==R4 (95us) revealed fp32 pk gives no throughput (157TF cap
// is FLOP-rate, not inst-rate): kernel sits at its VALU FLOP floor (~45us
// issue + overhead = 55us busy). Lever = fewer FLOPs: 5056 -> 3040 core
// FMA/thread. Structure keeps R12: 1024 persistent blocks x 4 rows,
// double-buffered coeff LDS (parity), next-row x prefetch before phase 3.

constexpr int kD = 2048, kN = 16, kB = 2, kL = 4096;
constexpr int kT   = 128;           // threads per block, 2 waves
constexpr int kCH  = kL / kT;       // 32 timesteps per thread
constexpr int kRPB = 4;             // rows per persistent block
constexpr int kGrid = (kB * kD) / kRPB;   // 1024 blocks = 4/CU
constexpr float kSCALE = 0.25f;     // sqrt(1/16)

__global__ __launch_bounds__(kT, 2) void fused_kernel(
    const float* __restrict__ x,     const float* __restrict__ alpha,
    const float* __restrict__ delta, const float* __restrict__ theta,
    const float* __restrict__ gamma, const float* __restrict__ omega,
    float* __restrict__ y,           float* __restrict__ hout)
{
    // per-row coefficient + publish LDS, double-buffered on parity r&1
    __shared__ float c2a[2][kN], ccc[2][kN], caa[2][kN], cbb[2][kN];
    __shared__ float cc1[2][kN], cc2[2][kN], cpr[2][kN];
    __shared__ float pubs[2][kN], pubp[2][kN];   // tid-63 (s, sp) publish

    const int tid   = threadIdx.x;
    const int llane = tid & 63;
    const bool w1   = (tid >= 64);
    const int row0  = blockIdx.x * kRPB;

    // --- prologue: issue row0's x burst (8 dwordx4 = 128 B/lane)
    float4 tb[8];
    {
        const float4* xp = (const float4*)(x + (size_t)row0 * kL + (size_t)tid * kCH);
#pragma unroll
        for (int k = 0; k < 8; k++) tb[k] = xp[k];
    }

#pragma unroll 1
    for (int r = 0; r < kRPB; ++r) {
        const int row = row0 + r;
        const int d   = row & (kD - 1);
        const int pp  = r & 1;

        // --- coefficients (threads 0..15); overlaps in-flight x loads.
        if (tid < kN) {
            int n = tid, i = d * kN + n;
            float p  = 1.0f / (1.0f + expf(-alpha[i]));
            float dd = 1.0f / (1.0f + expf(-delta[i]));
            float th = 1.0f / (1.0f + expf(-theta[d]));
            float phi = (float)(n + 1) * th * 0.39269908169872414f; // 2*pi/16
            float rr = 1.0f - p * dd;
            float sn, cs;
            sincosf(phi, &sn, &cs);
            float a = rr * cs, b = rr * sn;
            float gr = p * kSCALE * gamma[2 * i];
            float gi = -(p * kSCALE * gamma[2 * i + 1]);
            c2a[pp][n] = a + a;
            ccc[pp][n] = __builtin_fmaf(a, a, b * b);
            caa[pp][n] = a;
            cbb[pp][n] = b;
            cc1[pp][n] = gr;
            cc2[pp][n] = __builtin_fmaf(gi, b, -(gr * a));
            cpr[pp][n] = p;
        }

        // --- unpack this row's x (waits on in-flight burst)
        float xs[kCH];
#pragma unroll
        for (int k = 0; k < 8; k++) {
            xs[4*k+0] = tb[k].x; xs[4*k+1] = tb[k].y;
            xs[4*k+2] = tb[k].z; xs[4*k+3] = tb[k].w;
        }
        __syncthreads();                   // barrier #1: coeffs visible

        float twoa[kN], cc[kN];
#pragma unroll
        for (int n = 0; n < kN; n++) { twoa[n] = c2a[pp][n]; cc[n] = ccc[pp][n]; }

        // --- phase 1: local recurrence from zero (step 0 peeled: s=x0,sp=0).
        //     2 FMA/mode/step; sp update is a register rename.
        float ss[kN], sq[kN];
#pragma unroll
        for (int n = 0; n < kN; n++) { ss[n] = xs[0]; sq[n] = 0.0f; }
#pragma unroll
        for (int j = 1; j < kCH; j++) {
            float xj = xs[j];
#pragma unroll
            for (int n = 0; n < kN; n++) {
                float t  = __builtin_fmaf(-cc[n], sq[n], xj);
                float sn = __builtin_fmaf(twoa[n], ss[n], t);
                sq[n] = ss[n];
                ss[n] = sn;
            }
        }

        // --- M^32 as (al, be): start at M^2 = (2a, 1), 4 doublings.
        float al[kN], be[kN];
        {
            float aa[kN];
#pragma unroll
            for (int n = 0; n < kN; n++) {
                aa[n] = caa[pp][n];
                al[n] = twoa[n];
                be[n] = 1.0f;
            }
#pragma unroll
            for (int sdb = 0; sdb < 4; sdb++) {
#pragma unroll
                for (int n = 0; n < kN; n++) {
                    float t  = __builtin_fmaf(-cc[n], be[n], aa[n] * al[n]);
                    float nb = __builtin_fmaf(-cc[n], be[n] * be[n], al[n] * al[n]);
                    al[n] = (al[n] + al[n]) * t;
                    be[n] = nb;
                }
            }
        }

        // --- 6-round Hillis-Steele in (s,sp) space. Wave 1 accumulates
        //     W = M^(32*(llane+1)) as (Wa, Wb).
        float Wa[kN], Wb[kN];
#pragma unroll
        for (int n = 0; n < kN; n++) { Wa[n] = al[n]; Wb[n] = be[n]; }
#pragma unroll
        for (int rd = 0; rd < 6; rd++) {
            const int sh = 1 << rd;
#pragma unroll
            for (int n = 0; n < kN; n++) {
                float cb  = cc[n] * be[n];
                float e00 = __builtin_fmaf(twoa[n], al[n], -cb);
                float e01 = -(cc[n] * al[n]);
                float ts  = __shfl_up(ss[n], (unsigned)sh, 64);
                float tp  = __shfl_up(sq[n], (unsigned)sh, 64);
                if (llane >= sh) {
                    ss[n] = __builtin_fmaf(e00, ts,
                            __builtin_fmaf(e01, tp, ss[n]));
                    sq[n] = __builtin_fmaf(al[n], ts,
                            __builtin_fmaf(-cb, tp, sq[n]));
                }
            }
            if (w1 && (llane & sh)) {
#pragma unroll
                for (int n = 0; n < kN; n++) {
                    float t1 = Wa[n] * al[n];
                    float t2 = Wb[n] * be[n];
                    float t3 = __builtin_fmaf(Wa[n], be[n], al[n] * Wb[n]);
                    Wa[n] = __builtin_fmaf(twoa[n], t1, -(cc[n] * t3));
                    Wb[n] = __builtin_fmaf(-cc[n], t2, t1);
                }
            }
            if (rd < 5) {
#pragma unroll
                for (int n = 0; n < kN; n++) {
                    // double (al,be): a = twoa/2 -> a*al = 0.5*twoa*al
                    float t  = __builtin_fmaf(-cc[n], be[n],
                               0.5f * (twoa[n] * al[n]));
                    float nb = __builtin_fmaf(-cc[n], be[n] * be[n],
                                              al[n] * al[n]);
                    al[n] = (al[n] + al[n]) * t;
                    be[n] = nb;
                }
            }
        }

        // --- cross-wave combine: publish wave-0 lane-63 state.
        if (tid == 63) {
#pragma unroll
            for (int n = 0; n < kN; n++) { pubs[pp][n] = ss[n]; pubp[pp][n] = sq[n]; }
        }
        __syncthreads();                   // barrier #2
        if (w1) {
#pragma unroll
            for (int n = 0; n < kN; n++) {
                float cb  = cc[n] * Wb[n];
                float e00 = __builtin_fmaf(twoa[n], Wa[n], -cb);
                float e01 = -(cc[n] * Wa[n]);
                float ps  = pubs[pp][n], pq = pubp[pp][n];
                ss[n] = __builtin_fmaf(e00, ps,
                        __builtin_fmaf(e01, pq, ss[n]));
                sq[n] = __builtin_fmaf(Wa[n], ps,
                        __builtin_fmaf(-cb, pq, sq[n]));
            }
        }

        // --- final state (tid 127) -> hout: hr=p(s-a*sp), hi=p*b*sp
        if (tid == kT - 1) {
            float4* hp = (float4*)(hout + (size_t)row * (kN * 2));
#pragma unroll
            for (int k = 0; k < kN / 2; k++) {
                int n0 = 2 * k, n1 = 2 * k + 1;
                float hr0 = cpr[pp][n0] *
                            __builtin_fmaf(-caa[pp][n0], sq[n0], ss[n0]);
                float hi0 = cpr[pp][n0] * cbb[pp][n0] * sq[n0];
                float hr1 = cpr[pp][n1] *
                            __builtin_fmaf(-caa[pp][n1], sq[n1], ss[n1]);
                float hi1 = cpr[pp][n1] * cbb[pp][n1] * sq[n1];
                hp[k] = make_float4(hr0, hi0, hr1, hi1);
            }
        }

        // --- exclusive prefix: shift down one lane; wave-1 lane 0 takes
        //     the published wave-0 final; thread 0 takes zero.
#pragma unroll
        for (int n = 0; n < kN; n++) {
            float ts = __shfl_up(ss[n], 1, 64);
            float tp = __shfl_up(sq[n], 1, 64);
            ss[n] = ts; sq[n] = tp;
        }
        if (llane == 0) {
#pragma unroll
            for (int n = 0; n < kN; n++) {
                ss[n] = (tid == 0) ? 0.0f : pubs[pp][n];
                sq[n] = (tid == 0) ? 0.0f : pubp[pp][n];
            }
        }

        // --- PREFETCH next row's x: drains under phase 3 (~2.5us compute).
        if (r + 1 < kRPB) {
            const float4* xn = (const float4*)(x + (size_t)(row + 1) * kL +
                                               (size_t)tid * kCH);
#pragma unroll
            for (int k = 0; k < 8; k++) tb[k] = xn[k];
        }

        // --- phase 3: re-run chunk from exclusive init; 4 FMA/mode/step.
        float c1[kN], c2[kN];
#pragma unroll
        for (int n = 0; n < kN; n++) { c1[n] = cc1[pp][n]; c2[n] = cc2[pp][n]; }
        const float om = omega[d];

        float ys[kCH];
#pragma unroll
        for (int j = 0; j < kCH; j++) {
            float xj = xs[j];
            float acc0 = om * xj, acc1 = 0.0f, acc2 = 0.0f, acc3 = 0.0f;
#pragma unroll
            for (int n = 0; n < kN; n += 4) {
                float t, sn;
                t  = __builtin_fmaf(-cc[n],   sq[n],   xj);
                sn = __builtin_fmaf(twoa[n],  ss[n],   t);
                acc0 = __builtin_fmaf(c1[n],   sn,     acc0);
                acc0 = __builtin_fmaf(c2[n],   ss[n],  acc0);
                sq[n] = ss[n]; ss[n] = sn;
                t  = __builtin_fmaf(-cc[n+1], sq[n+1], xj);
                sn = __builtin_fmaf(twoa[n+1], ss[n+1], t);
                acc1 = __builtin_fmaf(c1[n+1], sn,     acc1);
                acc1 = __builtin_fmaf(c2[n+1], ss[n+1], acc1);
                sq[n+1] = ss[n+1]; ss[n+1] = sn;
                t  = __builtin_fmaf(-cc[n+2], sq[n+2], xj);
                sn = __builtin_fmaf(twoa[n+2], ss[n+2], t);
                acc2 = __builtin_fmaf(c1[n+2], sn,     acc2);
                acc2 = __builtin_fmaf(c2[n+2], ss[n+2], acc2);
                sq[n+2] = ss[n+2]; ss[n+2] = sn;
                t  = __builtin_fmaf(-cc[n+3], sq[n+3], xj);
                sn = __builtin_fmaf(twoa[n+3], ss[n+3], t);
                acc3 = __builtin_fmaf(c1[n+3], sn,     acc3);
                acc3 = __builtin_fmaf(c2[n+3], ss[n+3], acc3);
                sq[n+3] = ss[n+3]; ss[n+3] = sn;
            }
            ys[j] = (acc0 + acc1) + (acc2 + acc3);
        }

        // --- burst stores (8 back-to-back dwordx4 = 128 B/lane)
        float4* yp = (float4*)(y + (size_t)row * kL + (size_t)tid * kCH);
#pragma unroll
        for (int k = 0; k < 8; k++)
            yp[k] = make_float4(ys[4*k+0], ys[4*k+1], ys[4*k+2], ys[4*k+3]);
    }
}

extern "C" void kernel_launch(void* const* d_in, const int* in_sizes, int n_in,
                              void* d_out, int out_size, void* d_ws, size_t ws_size,
                              hipStream_t stream) {
    const float* x     = (const float*)d_in[0];
    const float* alpha = (const float*)d_in[1];
    const float* delta = (const float*)d_in[2];
    const float* theta = (const float*)d_in[3];
    const float* gamma = (const float*)d_in[4];
    const float* omega = (const float*)d_in[5];
    float* y    = (float*)d_out;
    float* hout = y + (size_t)kB * kD * kL;      // (B,D,N,2) after y

    fused_kernel<<<kGrid, kT, 0, stream>>>(x, alpha, delta, theta, gamma,
                                           omega, y, hout);
}

// Round 15
// 179.629 us; speedup vs baseline: 1.0765x; 1.0765x over previous
//
#include <hip/hip_runtime.h>
#include <math.h>

// ComplexEMA fused single-kernel (R14 = R11 chassis + second-order real
// recurrence; R13's -40% FLOP math WITHOUT R13's spills).
// y[b,d,t] = Re(sum_n gam_dn * h_dn[t]) + omega_d * x[b,d,t]
// h = p*u;  u' = q*u + x (complex, x REAL).  q = a+ib satisfies
// z^2 - 2a z + c = 0 (c=|q|^2) -> track ONE real state per mode:
//     s[t] = 2a*s[t-1] - c*s[t-2] + x[t]     (2 FMA; s[t-2] = rename)
// with ur = s - a*s_prev, ui = b*s_prev.  y-accum: Re(g*u) =
// c1*s_new + c2*s_old, c1=gr, c2=gi*b-gr*a.  Scan on (s,sp) with
// M^k = al*M - c*be*I (companion matrix char poly); doubling
// al'=2al(a*al-c*be), be'=al^2-c*be^2.  (All verified: R13 passed.)
//
// R13 post-mortem: persistent 4-row loop + held prefetch pushed liveness
// ~220; allocator capped VGPR=128 and SPILLED (WRITE 106MB vs 66 ideal,
// busy-time unchanged 59us). R14 reverts to the measured-best chassis
// (R4/R11 = 95us: 1 row/block, x in regs, 2 barriers) and diets registers:
// phase-3 output overwrites xs in place; c1/c2 fetched at phase 3 only;
// launch_bounds(128,1) so ~180 live regs allocate instead of spilling.

constexpr int kD = 2048, kN = 16, kB = 2, kL = 4096;
constexpr int kT  = 128;            // threads (= chunks) per row, 2 waves
constexpr int kCH = kL / kT;        // 32 timesteps per thread
constexpr float kSCALE = 0.25f;     // sqrt(1/16)

__global__ __launch_bounds__(kT, 1) void fused_kernel(
    const float* __restrict__ x,     const float* __restrict__ alpha,
    const float* __restrict__ delta, const float* __restrict__ theta,
    const float* __restrict__ gamma, const float* __restrict__ omega,
    float* __restrict__ y,           float* __restrict__ hout)
{
    __shared__ float c2a[kN], ccc[kN], caa[kN], cbb[kN];
    __shared__ float cc1[kN], cc2[kN], cpr[kN];
    __shared__ float pubs[kN], pubp[kN];     // wave-0 lane-63 (s,sp) publish

    const int row   = blockIdx.x;            // b*kD + d
    const int d     = row & (kD - 1);
    const int tid   = threadIdx.x;
    const int llane = tid & 63;
    const bool w1   = (tid >= 64);

    // --- burst-load 32 x samples to registers (8 dwordx4 = 128 B/lane);
    //     latency hides under the coefficient transcendentals.
    float xs[kCH];
    {
        const float4* xp = (const float4*)(x + (size_t)row * kL + (size_t)tid * kCH);
        float4 tb[8];
#pragma unroll
        for (int k = 0; k < 8; k++) tb[k] = xp[k];
#pragma unroll
        for (int k = 0; k < 8; k++) {
            xs[4*k+0] = tb[k].x; xs[4*k+1] = tb[k].y;
            xs[4*k+2] = tb[k].z; xs[4*k+3] = tb[k].w;
        }
    }

    // --- coefficients (threads 0..15, one n each)
    if (tid < kN) {
        int n = tid, i = d * kN + n;
        float p  = 1.0f / (1.0f + expf(-alpha[i]));
        float dd = 1.0f / (1.0f + expf(-delta[i]));
        float th = 1.0f / (1.0f + expf(-theta[d]));
        float phi = (float)(n + 1) * th * 0.39269908169872414f;  // 2*pi/16
        float rr = 1.0f - p * dd;
        float sn, cs;
        sincosf(phi, &sn, &cs);
        float a = rr * cs, b = rr * sn;
        float gr = p * kSCALE * gamma[2 * i];
        float gi = -(p * kSCALE * gamma[2 * i + 1]);
        c2a[n] = a + a;
        ccc[n] = __builtin_fmaf(a, a, b * b);
        caa[n] = a;
        cbb[n] = b;
        cc1[n] = gr;
        cc2[n] = __builtin_fmaf(gi, b, -(gr * a));
        cpr[n] = p;
    }
    __syncthreads();                         // barrier #1: coeffs visible

    float twoa[kN], cc[kN];
#pragma unroll
    for (int n = 0; n < kN; n++) { twoa[n] = c2a[n]; cc[n] = ccc[n]; }

    // --- phase 1: local recurrence from zero (step 0 peeled: s=x0, sp=0).
    //     2 FMA/mode/step.
    float ss[kN], sq[kN];
#pragma unroll
    for (int n = 0; n < kN; n++) { ss[n] = xs[0]; sq[n] = 0.0f; }
#pragma unroll
    for (int j = 1; j < kCH; j++) {
        float xj = xs[j];
#pragma unroll
        for (int n = 0; n < kN; n++) {
            float t  = __builtin_fmaf(-cc[n], sq[n], xj);
            float sn = __builtin_fmaf(twoa[n], ss[n], t);
            sq[n] = ss[n];
            ss[n] = sn;
        }
    }

    // --- M^32 as (al, be): start at M^2 = (2a, 1), 4 doublings.
    float al[kN], be[kN];
#pragma unroll
    for (int n = 0; n < kN; n++) { al[n] = twoa[n]; be[n] = 1.0f; }
#pragma unroll
    for (int sdb = 0; sdb < 4; sdb++) {
#pragma unroll
        for (int n = 0; n < kN; n++) {
            float t  = __builtin_fmaf(-cc[n], be[n], 0.5f * (twoa[n] * al[n]));
            float nb = __builtin_fmaf(-cc[n], be[n] * be[n], al[n] * al[n]);
            al[n] = (al[n] + al[n]) * t;
            be[n] = nb;
        }
    }

    // --- 6-round Hillis-Steele in (s,sp) space; wave 1 accumulates
    //     W = M^(32*(llane+1)) as (Wa, Wb).
    float Wa[kN], Wb[kN];
#pragma unroll
    for (int n = 0; n < kN; n++) { Wa[n] = al[n]; Wb[n] = be[n]; }
#pragma unroll
    for (int rd = 0; rd < 6; rd++) {
        const int sh = 1 << rd;
#pragma unroll
        for (int n = 0; n < kN; n++) {
            float cb  = cc[n] * be[n];
            float e00 = __builtin_fmaf(twoa[n], al[n], -cb);
            float e01 = -(cc[n] * al[n]);
            float ts  = __shfl_up(ss[n], (unsigned)sh, 64);
            float tp  = __shfl_up(sq[n], (unsigned)sh, 64);
            if (llane >= sh) {
                ss[n] = __builtin_fmaf(e00, ts, __builtin_fmaf(e01, tp, ss[n]));
                sq[n] = __builtin_fmaf(al[n], ts, __builtin_fmaf(-cb, tp, sq[n]));
            }
        }
        if (w1 && (llane & sh)) {
#pragma unroll
            for (int n = 0; n < kN; n++) {
                float t1 = Wa[n] * al[n];
                float t2 = Wb[n] * be[n];
                float t3 = __builtin_fmaf(Wa[n], be[n], al[n] * Wb[n]);
                Wa[n] = __builtin_fmaf(twoa[n], t1, -(cc[n] * t3));
                Wb[n] = __builtin_fmaf(-cc[n], t2, t1);
            }
        }
        if (rd < 5) {
#pragma unroll
            for (int n = 0; n < kN; n++) {
                float t  = __builtin_fmaf(-cc[n], be[n], 0.5f * (twoa[n] * al[n]));
                float nb = __builtin_fmaf(-cc[n], be[n] * be[n], al[n] * al[n]);
                al[n] = (al[n] + al[n]) * t;
                be[n] = nb;
            }
        }
    }

    // --- cross-wave combine: publish wave-0 lane-63 state, one barrier.
    if (tid == 63) {
#pragma unroll
        for (int n = 0; n < kN; n++) { pubs[n] = ss[n]; pubp[n] = sq[n]; }
    }
    __syncthreads();                         // barrier #2
    if (w1) {
#pragma unroll
        for (int n = 0; n < kN; n++) {
            float cb  = cc[n] * Wb[n];
            float e00 = __builtin_fmaf(twoa[n], Wa[n], -cb);
            float e01 = -(cc[n] * Wa[n]);
            float ps  = pubs[n], pq = pubp[n];
            ss[n] = __builtin_fmaf(e00, ps, __builtin_fmaf(e01, pq, ss[n]));
            sq[n] = __builtin_fmaf(Wa[n], ps, __builtin_fmaf(-cb, pq, sq[n]));
        }
    }

    // --- final state (tid 127) -> hout: hr = p*(s - a*sp), hi = p*b*sp
    if (tid == kT - 1) {
        float4* hp = (float4*)(hout + (size_t)row * (kN * 2));
#pragma unroll
        for (int k = 0; k < kN / 2; k++) {
            int n0 = 2 * k, n1 = 2 * k + 1;
            float hr0 = cpr[n0] * __builtin_fmaf(-caa[n0], sq[n0], ss[n0]);
            float hi0 = cpr[n0] * cbb[n0] * sq[n0];
            float hr1 = cpr[n1] * __builtin_fmaf(-caa[n1], sq[n1], ss[n1]);
            float hi1 = cpr[n1] * cbb[n1] * sq[n1];
            hp[k] = make_float4(hr0, hi0, hr1, hi1);
        }
    }

    // --- exclusive prefix: shift down one lane; wave-1 lane 0 takes the
    //     published wave-0 final; thread 0 takes zero.
#pragma unroll
    for (int n = 0; n < kN; n++) {
        float ts = __shfl_up(ss[n], 1, 64);
        float tp = __shfl_up(sq[n], 1, 64);
        ss[n] = ts; sq[n] = tp;
    }
    if (llane == 0) {
#pragma unroll
        for (int n = 0; n < kN; n++) {
            ss[n] = (tid == 0) ? 0.0f : pubs[n];
            sq[n] = (tid == 0) ? 0.0f : pubp[n];
        }
    }

    // --- phase 3: re-run chunk; 4 FMA/mode/step. Output overwrites xs[j]
    //     in place (xs[j] dead after its step) -> saves 32 VGPRs.
    float c1[kN], c2[kN];
#pragma unroll
    for (int n = 0; n < kN; n++) { c1[n] = cc1[n]; c2[n] = cc2[n]; }
    const float om = omega[d];

#pragma unroll
    for (int j = 0; j < kCH; j++) {
        float xj = xs[j];
        float acc0 = om * xj, acc1 = 0.0f, acc2 = 0.0f, acc3 = 0.0f;
#pragma unroll
        for (int n = 0; n < kN; n += 4) {
            float t, sn;
            t  = __builtin_fmaf(-cc[n],    sq[n],    xj);
            sn = __builtin_fmaf(twoa[n],   ss[n],    t);
            acc0 = __builtin_fmaf(c1[n],   sn,       acc0);
            acc0 = __builtin_fmaf(c2[n],   ss[n],    acc0);
            sq[n] = ss[n]; ss[n] = sn;
            t  = __builtin_fmaf(-cc[n+1],  sq[n+1],  xj);
            sn = __builtin_fmaf(twoa[n+1], ss[n+1],  t);
            acc1 = __builtin_fmaf(c1[n+1], sn,       acc1);
            acc1 = __builtin_fmaf(c2[n+1], ss[n+1],  acc1);
            sq[n+1] = ss[n+1]; ss[n+1] = sn;
            t  = __builtin_fmaf(-cc[n+2],  sq[n+2],  xj);
            sn = __builtin_fmaf(twoa[n+2], ss[n+2],  t);
            acc2 = __builtin_fmaf(c1[n+2], sn,       acc2);
            acc2 = __builtin_fmaf(c2[n+2], ss[n+2],  acc2);
            sq[n+2] = ss[n+2]; ss[n+2] = sn;
            t  = __builtin_fmaf(-cc[n+3],  sq[n+3],  xj);
            sn = __builtin_fmaf(twoa[n+3], ss[n+3],  t);
            acc3 = __builtin_fmaf(c1[n+3], sn,       acc3);
            acc3 = __builtin_fmaf(c2[n+3], ss[n+3],  acc3);
            sq[n+3] = ss[n+3]; ss[n+3] = sn;
        }
        xs[j] = (acc0 + acc1) + (acc2 + acc3);   // y value, in place
    }

    // --- burst stores (8 back-to-back dwordx4 = 128 B/lane)
    float4* yp = (float4*)(y + (size_t)row * kL + (size_t)tid * kCH);
#pragma unroll
    for (int k = 0; k < 8; k++)
        yp[k] = make_float4(xs[4*k+0], xs[4*k+1], xs[4*k+2], xs[4*k+3]);
}

extern "C" void kernel_launch(void* const* d_in, const int* in_sizes, int n_in,
                              void* d_out, int out_size, void* d_ws, size_t ws_size,
                              hipStream_t stream) {
    const float* x     = (const float*)d_in[0];
    const float* alpha = (const float*)d_in[1];
    const float* delta = (const float*)d_in[2];
    const float* theta = (const float*)d_in[3];
    const float* gamma = (const float*)d_in[4];
    const float* omega = (const float*)d_in[5];
    float* y    = (float*)d_out;
    float* hout = y + (size_t)kB * kD * kL;      // (B,D,N,2) after y

    fused_kernel<<<kB * kD, kT, 0, stream>>>(x, alpha, delta, theta, gamma,
                                             omega, y, hout);
}